// Round 6
// baseline (259.547 us; speedup 1.0000x reference)
//
#include <hip/hip_runtime.h>
#include <math.h>

#define N_EDGES_C 1048576
#define N_TOTAL_C 65536

typedef _Float16 h2v __attribute__((ext_vector_type(2)));
typedef int i4v __attribute__((ext_vector_type(4)));             // native vec4 for nontemporal builtins

#if defined(__has_builtin)
#if __has_builtin(__builtin_amdgcn_fdot2)
#define HAS_FDOT2 1
#endif
#if __has_builtin(__builtin_amdgcn_rcpf)
#define HAS_RCPF 1
#endif
#endif

__device__ __forceinline__ float fdot2(h2v a, h2v b, float c) {
#ifdef HAS_FDOT2
    return __builtin_amdgcn_fdot2(a, b, c, false);
#else
    return c + (float)a.x * (float)b.x + (float)a.y * (float)b.y;
#endif
}

__device__ __forceinline__ float fast_rcp(float x) {
#ifdef HAS_RCPF
    return __builtin_amdgcn_rcpf(x);
#else
    return 1.0f / x;
#endif
}
// fast sigmoid/tanh: v_exp_f32 + v_rcp_f32 (~1ulp each) instead of libm calls.
__device__ __forceinline__ float sigf(float x){ return fast_rcp(1.0f + __expf(-x)); }
__device__ __forceinline__ float tanh_fast(float x){ return fmaf(2.0f, fast_rcp(1.0f + __expf(-2.0f*x)), -1.0f); }
__device__ __forceinline__ float lrelu(float x){ return (x>=0.f)? x : 0.2f*x; }

// cnt layout (round-17): per-slice ROTATION to break 64KB pow-2 stride channel
// aliasing: element (slice s, word w) lives at s*16384 + ((w + s*521) & 16383).
// slice_prefix walks stride (16384+521)*4B (non-pow2); edge_hist writeout and
// edge_scatter reads apply the same formula. Coalescing preserved (uniform
// shift per slice).
#define CNT_ROT(s, w) ((size_t)(s)*16384 + (((unsigned)(w) + (unsigned)(s)*521u) & 16383u))

// xpp row layout (round-2 PROVEN): NODE-MAJOR, 128 halfs (256 B) per node =
// 8 head slots x 16 halfs: [ch0..ch11 fp16 | asrc f32 | adst f32]
// gat floor: 117 MB FETCH == compulsory (8 XCDs x ~15 MB) at ~2.7 TB/s
// random-fetch fabric rate -> 44 us ~ structural floor (r3 head-major:
// request-bound 76us; r4 4MB slices: L2 thrash 90us).

// ---------------- 1. node transform (8 thr/node, coalesced 2KB wave stores) ----------------
__global__ void prep_kernel(const float* __restrict__ x, const float* __restrict__ Wg,
                            const float* __restrict__ a_src, const float* __restrict__ a_dst,
                            _Float16* __restrict__ xpp)
{
    int tid = threadIdx.x;
    __shared__ float Ws[12*96];
    __shared__ float as_s[96], ad_s[96];
    for (int i = tid; i < 1152; i += 256) Ws[i] = Wg[i];
    if (tid < 96) { as_s[tid] = a_src[tid]; ad_s[tid] = a_dst[tid]; }
    __syncthreads();
    int gid = blockIdx.x * 256 + tid;
    int n = gid >> 3;
    int h = gid & 7;
    const float4* xv = (const float4*)(x + (size_t)n * 12);
    float4 v0 = xv[0], v1 = xv[1], v2 = xv[2];
    float xr[12] = {v0.x,v0.y,v0.z,v0.w, v1.x,v1.y,v1.z,v1.w, v2.x,v2.y,v2.z,v2.w};
    float xp_[12];
    #pragma unroll
    for (int c = 0; c < 12; c++) {
        float acc = 0.f;
        #pragma unroll
        for (int k = 0; k < 12; k++) acc += xr[k] * Ws[k*96 + h*12 + c];
        xp_[c] = acc;
    }
    float sa = 0.f, sd = 0.f;
    #pragma unroll
    for (int c = 0; c < 12; c++) { sa += xp_[c]*as_s[h*12+c]; sd += xp_[c]*ad_s[h*12+c]; }
    union { _Float16 hh[16]; float ff[8]; float4 f4[2]; } s;
    #pragma unroll
    for (int c = 0; c < 12; c++) s.hh[c] = (_Float16)xp_[c];
    s.ff[6] = sa;
    s.ff[7] = sd;
    float4* o = (float4*)(xpp + (size_t)gid * 16);
    o[0] = s.f4[0];
    o[1] = s.f4[1];
}

// ---------------- 2a. 8-bit LDS histogram rank builder (single pass, all 64K nodes) ----------------
// deg ~ Poisson(16) (max ~50) so every count/offset fits a byte; per-(slice,node)
// count <= ~6. 128 slices x 8192 edges; rank8 packs 4 edge-ranks per word.
// Also zeroes the slice_prefix barrier counter (stream order guarantees
// visibility before slice_prefix runs).
__global__ __launch_bounds__(256)
void edge_hist(const int* __restrict__ ei, unsigned* __restrict__ cnt,
               unsigned* __restrict__ rank8, int* __restrict__ ctr)
{
    __shared__ unsigned hist[16384];           // 64 KB: 65536 nodes x 8-bit
    int tid = threadIdx.x;
    int slice = blockIdx.x;                    // 0..127
    if (slice == 0 && tid == 0) *ctr = 0;
    for (int i = tid; i < 16384; i += 256) hist[i] = 0;
    __syncthreads();
    const i4v* dst4 = (const i4v*)(ei + N_EDGES_C) + slice*2048;
    for (int i = tid; i < 2048; i += 256) {
        i4v d = __builtin_nontemporal_load(&dst4[i]);
        int dd[4] = {d.x, d.y, d.z, d.w};
        unsigned packed = 0;
        #pragma unroll
        for (int j = 0; j < 4; j++) {
            int dj = dd[j];
            unsigned sh = (unsigned)(dj & 3) << 3;
            unsigned old = atomicAdd(&hist[dj >> 2], 1u << sh);
            packed |= ((old >> sh) & 0xffu) << (j*8);
        }
        __builtin_nontemporal_store(packed, &rank8[slice*2048 + i]);
    }
    __syncthreads();
    for (int i = tid; i < 16384; i += 256) cnt[CNT_ROT(slice, i)] = hist[i];
}

// ---------------- 2b. SWAR slice prefix + FULL rowptr scan (device barrier) ----------------
// Round-17: single kernel replaces slice_prefix + scan_mid + scan_out.
// 128 blocks x 128 thr (trivially co-resident on 256 CUs): block-local SWAR
// scan -> publish chunksum -> device-scope spin barrier -> every block scans
// the 128 chunksums and writes its final rowptr int4. Bit-identical rowptr.
__global__ __launch_bounds__(128)
void slice_prefix(unsigned* __restrict__ cnt, int* __restrict__ rowptr,
                  int* __restrict__ chunksum, int* __restrict__ ctr)
{
    __shared__ int ss[128];
    int tid = threadIdx.x;
    int bid = blockIdx.x;
    int w = bid*128 + tid;                     // 0..16383, 4 nodes per word
    unsigned run = 0;
    #pragma unroll 1
    for (int s = 0; s < 128; s += 32) {        // 32-deep load batching
        unsigned v[32];
        #pragma unroll
        for (int k = 0; k < 32; k++) v[k] = cnt[CNT_ROT(s+k, w)];
        #pragma unroll
        for (int k = 0; k < 32; k++) {
            cnt[CNT_ROT(s+k, w)] = run;
            run += v[k];                        // byte-lane add, carry-free
        }
    }
    int d0 = (int)(run & 255u), d1 = (int)((run >> 8) & 255u);
    int d2 = (int)((run >> 16) & 255u), d3 = (int)(run >> 24);
    int tsum = d0 + d1 + d2 + d3;
    ss[tid] = tsum;
    __syncthreads();
    for (int off = 1; off < 128; off <<= 1) {
        int t = (tid >= off) ? ss[tid - off] : 0;
        __syncthreads();
        ss[tid] += t;
        __syncthreads();
    }
    int ex = ss[tid] - tsum;                   // block-exclusive prefix

    if (tid == 127) {
        __hip_atomic_store(&chunksum[bid], ss[127], __ATOMIC_RELEASE, __HIP_MEMORY_SCOPE_AGENT);
        atomicAdd(ctr, 1);                     // device-scope by default
    }
    if (tid == 0) {
        while (__hip_atomic_load(ctr, __ATOMIC_ACQUIRE, __HIP_MEMORY_SCOPE_AGENT) < 128)
            __builtin_amdgcn_s_sleep(2);
    }
    __syncthreads();

    int csv = __hip_atomic_load(&chunksum[tid], __ATOMIC_RELAXED, __HIP_MEMORY_SCOPE_AGENT);
    ss[tid] = csv;
    __syncthreads();
    for (int off = 1; off < 128; off <<= 1) {
        int t = (tid >= off) ? ss[tid - off] : 0;
        __syncthreads();
        ss[tid] += t;
        __syncthreads();
    }
    int goff = (bid == 0) ? 0 : ss[bid-1];     // global chunk offset
    int4 r;
    r.x = ex + goff;
    r.y = r.x + d0;
    r.z = r.y + d1;
    r.w = r.z + d2;
    ((int4*)rowptr)[w] = r;
    if (bid == 0 && tid == 127) rowptr[65536] = ss[127];
}

// ---------------- 2d. read-once LDS-staged CSR scatter ----------------
__global__ __launch_bounds__(256)
void edge_scatter(const int* __restrict__ ei, const unsigned* __restrict__ rank8,
                  const unsigned* __restrict__ cnt, const int* __restrict__ rowptr,
                  int* __restrict__ csr)
{
    __shared__ unsigned pos_s[2048];           // pos | (dst-group << 24)
    __shared__ int src_s[2048];
    int slice = blockIdx.x >> 2;               // 0..127
    int quar  = blockIdx.x & 3;                // 0..3
    int base = slice*2048 + quar*512;          // i4v units
    const i4v* dst4 = (const i4v*)(ei + N_EDGES_C);
    const i4v* src4 = (const i4v*)ei;
    for (int i = threadIdx.x; i < 512; i += 256) {
        int idx = base + i;
        i4v d = __builtin_nontemporal_load(&dst4[idx]);
        i4v s = __builtin_nontemporal_load(&src4[idx]);
        unsigned r = __builtin_nontemporal_load(&rank8[idx]);
        int dd[4] = {d.x, d.y, d.z, d.w};
        int ss[4] = {s.x, s.y, s.z, s.w};
        #pragma unroll
        for (int j = 0; j < 4; j++) {
            int dj = dd[j];
            unsigned word = cnt[CNT_ROT(slice, dj >> 2)];
            int so = (int)((word >> ((unsigned)(dj & 3) << 3)) & 0xffu);
            int rk = (int)((r >> (j*8)) & 0xffu);
            unsigned pos = (unsigned)(rowptr[dj] + so + rk);
            pos_s[i*4 + j] = pos | ((unsigned)(dj >> 13) << 24);
            src_s[i*4 + j] = ss[j];
        }
    }
    __syncthreads();
    #pragma unroll 1
    for (unsigned g = 0; g < 8; g++) {
        for (int e = threadIdx.x; e < 2048; e += 256) {
            unsigned pw = pos_s[e];
            if ((pw >> 24) == g) csr[pw & 0xFFFFFFu] = src_s[e];
        }
    }
}

// ---------------- 3. per-(node,head) softmax aggregation + BN + log_softmax ----------------
// Round-2 proven form: node-major gathers (8 lanes share a 256B row -> 2
// coalesced 128B requests/edge), x4 neighbor unroll, fused shfl-mean +
// BN + log_softmax. 44 us ~= 117 MB compulsory / 2.7 TB/s fabric rate.
__global__ void gat_aggregate(const _Float16* __restrict__ xpp,
                              const int* __restrict__ rowptr, const int* __restrict__ csr_src,
                              const float* __restrict__ gat_bias, const float* __restrict__ bn_gamma,
                              const float* __restrict__ bn_beta, const float* __restrict__ bn_mean,
                              const float* __restrict__ bn_var, float* __restrict__ seq)
{
    int gid = blockIdx.x * 256 + threadIdx.x;
    int n = gid >> 3;
    int h = gid & 7;

    float acc[12];
    float adst_n, d;
    {
        const float4* p = (const float4*)(xpp + (size_t)n*128 + h*16);
        float4 f0 = p[0], f1 = p[1];
        adst_n = f1.w;
        float w = __expf(lrelu(f1.z + adst_n));   // self-loop term
        d = w;
        h2v c0 = __builtin_bit_cast(h2v, f0.x), c1 = __builtin_bit_cast(h2v, f0.y);
        h2v c2 = __builtin_bit_cast(h2v, f0.z), c3 = __builtin_bit_cast(h2v, f0.w);
        h2v c4 = __builtin_bit_cast(h2v, f1.x), c5 = __builtin_bit_cast(h2v, f1.y);
        acc[0]=w*(float)c0.x; acc[1]=w*(float)c0.y; acc[2]=w*(float)c1.x; acc[3]=w*(float)c1.y;
        acc[4]=w*(float)c2.x; acc[5]=w*(float)c2.y; acc[6]=w*(float)c3.x; acc[7]=w*(float)c3.y;
        acc[8]=w*(float)c4.x; acc[9]=w*(float)c4.y; acc[10]=w*(float)c5.x; acc[11]=w*(float)c5.y;
    }

    auto accum = [&](float4 f0, float4 f1) {
        float w = __expf(lrelu(f1.z + adst_n));
        d += w;
        h2v c0 = __builtin_bit_cast(h2v, f0.x), c1 = __builtin_bit_cast(h2v, f0.y);
        h2v c2 = __builtin_bit_cast(h2v, f0.z), c3 = __builtin_bit_cast(h2v, f0.w);
        h2v c4 = __builtin_bit_cast(h2v, f1.x), c5 = __builtin_bit_cast(h2v, f1.y);
        acc[0]+=w*(float)c0.x; acc[1]+=w*(float)c0.y; acc[2]+=w*(float)c1.x; acc[3]+=w*(float)c1.y;
        acc[4]+=w*(float)c2.x; acc[5]+=w*(float)c2.y; acc[6]+=w*(float)c3.x; acc[7]+=w*(float)c3.y;
        acc[8]+=w*(float)c4.x; acc[9]+=w*(float)c4.y; acc[10]+=w*(float)c5.x; acc[11]+=w*(float)c5.y;
    };

    int beg = rowptr[n], end = rowptr[n+1];
    const _Float16* xh = xpp + (size_t)h * 16;
    int i = beg;
    for (; i + 4 <= end; i += 4) {
        int s0 = csr_src[i+0];
        int s1 = csr_src[i+1];
        int s2 = csr_src[i+2];
        int s3 = csr_src[i+3];
        const float4* p0 = (const float4*)(xh + (size_t)s0*128);
        const float4* p1 = (const float4*)(xh + (size_t)s1*128);
        const float4* p2 = (const float4*)(xh + (size_t)s2*128);
        const float4* p3 = (const float4*)(xh + (size_t)s3*128);
        float4 a0 = p0[0], b0 = p0[1];
        float4 a1 = p1[0], b1 = p1[1];
        float4 a2 = p2[0], b2 = p2[1];
        float4 a3 = p3[0], b3 = p3[1];
        accum(a0, b0);
        accum(a1, b1);
        accum(a2, b2);
        accum(a3, b3);
    }
    for (; i < end; i++) {
        int src = csr_src[i];
        const float4* p = (const float4*)(xh + (size_t)src*128);
        float4 f0 = p[0], f1 = p[1];
        accum(f0, f1);
    }

    float inv = 1.0f / (d + 1e-16f);
    float res[12];
    #pragma unroll
    for (int c = 0; c < 12; c++) {
        float v = acc[c] * inv;
        v += __shfl_xor(v, 1);
        v += __shfl_xor(v, 2);
        v += __shfl_xor(v, 4);
        res[c] = v * 0.125f;     // mean over 8 heads
    }
    if (h == 0) {
        float vals[12];
        float mx = -1e30f;
        #pragma unroll
        for (int c = 0; c < 12; c++) {
            float v = res[c] + gat_bias[c];
            v = (v - bn_mean[c]) * rsqrtf(bn_var[c] + 1e-5f) * bn_gamma[c] + bn_beta[c];
            vals[c] = v;
            mx = fmaxf(mx, v);
        }
        float sum = 0.f;
        #pragma unroll
        for (int c = 0; c < 12; c++) sum += __expf(vals[c] - mx);
        float lse = __logf(sum) + mx;
        #pragma unroll
        for (int c = 0; c < 12; c++) seq[(size_t)c * N_TOTAL_C + n] = vals[c] - lse;
    }
}

// ---------------- 4. X1 = seq(384x2048) @ w_ih1(128x2048)^T, split-K x4 ----------------
// Round-17: split-K 16->4 (192 blocks still >= 1/CU): 4x fewer float atomics.
__global__ void gemm_x1(const float* __restrict__ A, const float* __restrict__ B,
                        float* __restrict__ C)
{
    __shared__ float As[32][33], Bs[32][33];
    const int K = 2048, N = 128;
    int tid = threadIdx.x;
    int tx = tid & 31, ty = tid >> 5;
    int bm = blockIdx.x * 32, bn = blockIdx.y * 32;
    int kbase = blockIdx.z * 512;
    float acc[4] = {0.f,0.f,0.f,0.f};
    for (int kk = 0; kk < 512; kk += 32) {
        int k0 = kbase + kk;
        #pragma unroll
        for (int i = 0; i < 4; i++) {
            int r = ty + i*8;
            As[r][tx] = A[(size_t)(bm + r) * K + k0 + tx];
            Bs[r][tx] = B[(size_t)(bn + r) * K + k0 + tx];
        }
        __syncthreads();
        #pragma unroll
        for (int k = 0; k < 32; k++) {
            float bv = Bs[tx][k];
            #pragma unroll
            for (int i = 0; i < 4; i++) acc[i] += As[ty + i*8][k] * bv;
        }
        __syncthreads();
    }
    #pragma unroll
    for (int i = 0; i < 4; i++)
        atomicAdd(&C[(size_t)(bm + ty + i*8) * N + bn + tx], acc[i]);
}

// ---------------- 5. fused LSTM1(2048->32) + LSTM2(32->128) ----------------
__global__ __launch_bounds__(512)
void lstm_fused(const float* __restrict__ X1, const float* __restrict__ w_hh1,
                const float* __restrict__ b_ih1, const float* __restrict__ b_hh1,
                const float* __restrict__ w_ih2, const float* __restrict__ w_hh2,
                const float* __restrict__ b_ih2, const float* __restrict__ b_hh2,
                float* __restrict__ H2)
{
    __shared__ float whh1[128*33];             // padded stride 33
    __shared__ float b1s[128];
    __shared__ float h1[32], c1[32];
    __shared__ __align__(16) _Float16 h1s[32];
    __shared__ __align__(16) _Float16 h2s[128];
    __shared__ float c2[128];
    __shared__ float g1s[128], g2s[512];
    int tid = threadIdx.x;
    int b = blockIdx.x;

    h2v whh[64];
    {
        const float2* wh = (const float2*)(w_hh2 + (size_t)tid * 128);
        #pragma unroll
        for (int k = 0; k < 64; k++) {
            float2 v = wh[k];
            h2v t; t.x = (_Float16)v.x; t.y = (_Float16)v.y;
            whh[k] = t;
        }
    }
    h2v wih[16];
    {
        const float2* wi = (const float2*)(w_ih2 + (size_t)tid * 32);
        #pragma unroll
        for (int k = 0; k < 16; k++) {
            float2 v = wi[k];
            h2v t; t.x = (_Float16)v.x; t.y = (_Float16)v.y;
            wih[k] = t;
        }
    }
    float b2 = b_ih2[tid] + b_hh2[tid];

    for (int i = tid; i < 128*32; i += 512) whh1[(i >> 5)*33 + (i & 31)] = w_hh1[i];
    if (tid < 128) b1s[tid] = b_ih1[tid] + b_hh1[tid];
    if (tid < 32)  { h1[tid] = 0.f; c1[tid] = 0.f; h1s[tid] = (_Float16)0.f; }
    if (tid < 128) { c2[tid] = 0.f; h2s[tid] = (_Float16)0.f; }

    float xv = 0.f;
    if (tid < 128) xv = X1[((size_t)0*32 + b)*128 + tid];   // t=0 row
    __syncthreads();

    for (int t = 0; t < 12; t++) {
        float xv_next = 0.f;
        if (t < 11 && tid < 128) xv_next = X1[((size_t)(t+1)*32 + b)*128 + tid];

        float p0 = b2, p1 = 0.f, p2 = 0.f, p3 = 0.f;
        #pragma unroll
        for (int j = 0; j < 16; j++) {
            float4 f = ((const float4*)h2s)[j];
            p0 = fdot2(__builtin_bit_cast(h2v, f.x), whh[j*4+0], p0);
            p1 = fdot2(__builtin_bit_cast(h2v, f.y), whh[j*4+1], p1);
            p2 = fdot2(__builtin_bit_cast(h2v, f.z), whh[j*4+2], p2);
            p3 = fdot2(__builtin_bit_cast(h2v, f.w), whh[j*4+3], p3);
        }
        float acc2 = (p0 + p1) + (p2 + p3);

        if (tid < 128) {
            const float* wr = &whh1[tid * 33];
            float acc = xv + b1s[tid];
            #pragma unroll
            for (int k = 0; k < 32; k++) acc += h1[k] * wr[k];
            g1s[tid] = acc;
        }
        __syncthreads();
        if (tid < 32) {
            float ig = sigf(g1s[tid]), fg = sigf(g1s[32+tid]);
            float gg = tanh_fast(g1s[64+tid]), og = sigf(g1s[96+tid]);
            float cn = fg * c1[tid] + ig * gg;
            c1[tid] = cn;
            float hn = og * tanh_fast(cn);
            h1[tid] = hn;
            h1s[tid] = (_Float16)hn;
        }
        __syncthreads();
        {
            float q0 = 0.f, q1 = 0.f, q2 = 0.f, q3 = 0.f;
            #pragma unroll
            for (int j = 0; j < 4; j++) {
                float4 f = ((const float4*)h1s)[j];
                q0 = fdot2(__builtin_bit_cast(h2v, f.x), wih[j*4+0], q0);
                q1 = fdot2(__builtin_bit_cast(h2v, f.y), wih[j*4+1], q1);
                q2 = fdot2(__builtin_bit_cast(h2v, f.z), wih[j*4+2], q2);
                q3 = fdot2(__builtin_bit_cast(h2v, f.w), wih[j*4+3], q3);
            }
            g2s[tid] = acc2 + (q0 + q1) + (q2 + q3);
        }
        __syncthreads();
        if (tid < 128) {
            float ig = sigf(g2s[tid]), fg = sigf(g2s[128+tid]);
            float gg = tanh_fast(g2s[256+tid]), og = sigf(g2s[384+tid]);
            float cn = fg * c2[tid] + ig * gg;
            c2[tid] = cn;
            float hn = og * tanh_fast(cn);
            h2s[tid] = (_Float16)hn;
            if (t >= 3) H2[((size_t)t*32 + b)*128 + tid] = hn;
        }
        __syncthreads();
        xv = xv_next;
    }
}

// ---------------- 6. out = H2[3:] (288x128) @ lin_w(2048x128)^T + lin_b ----------------
__global__ void gemm_out(const float* __restrict__ A, const float* __restrict__ B,
                         const float* __restrict__ bias, float* __restrict__ out)
{
    __shared__ float As[32][33], Bs[32][33];
    const int K = 128;
    int tid = threadIdx.x;
    int tx = tid & 31, ty = tid >> 5;
    int bm = blockIdx.x * 32, bn = blockIdx.y * 32;
    float acc[4] = {0.f,0.f,0.f,0.f};
    for (int k0 = 0; k0 < K; k0 += 32) {
        #pragma unroll
        for (int i = 0; i < 4; i++) {
            int r = ty + i*8;
            As[r][tx] = A[(size_t)(bm + r) * K + k0 + tx];
            Bs[r][tx] = B[(size_t)(bn + r) * K + k0 + tx];
        }
        __syncthreads();
        #pragma unroll
        for (int kk = 0; kk < 32; kk++) {
            float bv = Bs[tx][kk];
            #pragma unroll
            for (int i = 0; i < 4; i++) acc[i] += As[ty + i*8][kk] * bv;
        }
        __syncthreads();
    }
    int j = blockIdx.x;            // time slot within last 9
    int nn = bn + tx;
    float bv = bias[nn];
    #pragma unroll
    for (int i = 0; i < 4; i++) {
        int bb = ty + i*8;
        out[((size_t)bb * 2048 + nn) * 9 + j] = acc[i] + bv;
    }
}

extern "C" void kernel_launch(void* const* d_in, const int* in_sizes, int n_in,
                              void* d_out, int out_size, void* d_ws, size_t ws_size,
                              hipStream_t stream)
{
    const float* x        = (const float*)d_in[0];
    const int*   ei       = (const int*)  d_in[1];
    const float* W_gat    = (const float*)d_in[2];
    const float* a_src    = (const float*)d_in[3];
    const float* a_dst    = (const float*)d_in[4];
    const float* gat_bias = (const float*)d_in[5];
    const float* bn_gamma = (const float*)d_in[6];
    const float* bn_beta  = (const float*)d_in[7];
    const float* bn_mean  = (const float*)d_in[8];
    const float* bn_var   = (const float*)d_in[9];
    const float* w_ih1    = (const float*)d_in[10];
    const float* w_hh1    = (const float*)d_in[11];
    const float* b_ih1    = (const float*)d_in[12];
    const float* b_hh1    = (const float*)d_in[13];
    const float* w_ih2    = (const float*)d_in[14];
    const float* w_hh2    = (const float*)d_in[15];
    const float* b_ih2    = (const float*)d_in[16];
    const float* b_hh2    = (const float*)d_in[17];
    const float* lin_w    = (const float*)d_in[18];
    const float* lin_b    = (const float*)d_in[19];
    float* out = (float*)d_out;

    float* ws = (float*)d_ws;                     // all offsets in float slots (x4 bytes)
    _Float16* xpp = (_Float16*)ws;                // 65536*128 halfs = 4194304 slots (16 MB, node-major)
    float* seq  = ws + 4194304;                   // 786432
    float* X1   = seq + 786432;                   // 49152
    float* H2   = X1  + 49152;                    // 49152
    int* rowptr = (int*)(H2 + 49152);             // 65537 (reserve 65544, 16B-aligned)
    int* deg    = rowptr + 65544;                 // 65536 (reused: chunksum[128], ctr)
    unsigned* cnt = (unsigned*)(deg + 65536);     // 128*16384 = 2097152 words (8 MB, rotated layout)
    unsigned* rank8 = cnt + 2097152;              // 262144 words (1 MB)
    int* csr    = (int*)(rank8 + 262144);         // 1048576
    // total ~34 MB of d_ws

    int* chunksum = deg;
    int* ctr      = deg + 256;

    hipMemsetAsync(X1, 0, 49152 * sizeof(float), stream);
    prep_kernel <<<2048, 256, 0, stream>>>(x, W_gat, a_src, a_dst, xpp);
    edge_hist   <<<128, 256, 0, stream>>>(ei, cnt, rank8, ctr);
    slice_prefix<<<128, 128, 0, stream>>>(cnt, rowptr, chunksum, ctr);
    edge_scatter<<<512, 256, 0, stream>>>(ei, rank8, cnt, rowptr, csr);
    gat_aggregate<<<2048, 256, 0, stream>>>(xpp, rowptr, csr,
                                            gat_bias, bn_gamma, bn_beta, bn_mean, bn_var, seq);
    gemm_x1<<<dim3(12, 4, 4), 256, 0, stream>>>(seq, w_ih1, X1);
    lstm_fused<<<32, 512, 0, stream>>>(X1, w_hh1, b_ih1, b_hh1, w_ih2, w_hh2, b_ih2, b_hh2, H2);
    gemm_out<<<dim3(9, 64), 256, 0, stream>>>(H2 + 96*128, lin_w, lin_b, out);
}

// Round 7
// 240.959 us; speedup vs baseline: 1.0771x; 1.0771x over previous
//
#include <hip/hip_runtime.h>
#include <math.h>

#define N_EDGES_C 1048576
#define N_TOTAL_C 65536

typedef _Float16 h2v __attribute__((ext_vector_type(2)));
typedef int i4v __attribute__((ext_vector_type(4)));             // native vec4 for nontemporal builtins

#if defined(__has_builtin)
#if __has_builtin(__builtin_amdgcn_fdot2)
#define HAS_FDOT2 1
#endif
#if __has_builtin(__builtin_amdgcn_rcpf)
#define HAS_RCPF 1
#endif
#endif

__device__ __forceinline__ float fdot2(h2v a, h2v b, float c) {
#ifdef HAS_FDOT2
    return __builtin_amdgcn_fdot2(a, b, c, false);
#else
    return c + (float)a.x * (float)b.x + (float)a.y * (float)b.y;
#endif
}

__device__ __forceinline__ float fast_rcp(float x) {
#ifdef HAS_RCPF
    return __builtin_amdgcn_rcpf(x);
#else
    return 1.0f / x;
#endif
}
// fast sigmoid/tanh: v_exp_f32 + v_rcp_f32 (~1ulp each) instead of libm calls.
__device__ __forceinline__ float sigf(float x){ return fast_rcp(1.0f + __expf(-x)); }
__device__ __forceinline__ float tanh_fast(float x){ return fmaf(2.0f, fast_rcp(1.0f + __expf(-2.0f*x)), -1.0f); }
__device__ __forceinline__ float lrelu(float x){ return (x>=0.f)? x : 0.2f*x; }

// xpp row layout (round-2 PROVEN): NODE-MAJOR, 128 halfs (256 B) per node =
// 8 head slots x 16 halfs: [ch0..ch11 fp16 | asrc f32 | adst f32]
// gat floor: 117 MB FETCH == compulsory (8 XCDs x ~15 MB) at ~2.7 TB/s
// random-fetch fabric rate -> 44 us ~ structural floor (r3 head-major:
// request-bound 76us; r4 4MB slices: L2 thrash 90us; r6 rotation+fused-scan
// +splitK4: regression, reverted).

// ---------------- 1. node transform (8 thr/node, coalesced 2KB wave stores) ----------------
__global__ void prep_kernel(const float* __restrict__ x, const float* __restrict__ Wg,
                            const float* __restrict__ a_src, const float* __restrict__ a_dst,
                            _Float16* __restrict__ xpp)
{
    int tid = threadIdx.x;
    __shared__ float Ws[12*96];
    __shared__ float as_s[96], ad_s[96];
    for (int i = tid; i < 1152; i += 256) Ws[i] = Wg[i];
    if (tid < 96) { as_s[tid] = a_src[tid]; ad_s[tid] = a_dst[tid]; }
    __syncthreads();
    int gid = blockIdx.x * 256 + tid;
    int n = gid >> 3;
    int h = gid & 7;
    const float4* xv = (const float4*)(x + (size_t)n * 12);
    float4 v0 = xv[0], v1 = xv[1], v2 = xv[2];
    float xr[12] = {v0.x,v0.y,v0.z,v0.w, v1.x,v1.y,v1.z,v1.w, v2.x,v2.y,v2.z,v2.w};
    float xp_[12];
    #pragma unroll
    for (int c = 0; c < 12; c++) {
        float acc = 0.f;
        #pragma unroll
        for (int k = 0; k < 12; k++) acc += xr[k] * Ws[k*96 + h*12 + c];
        xp_[c] = acc;
    }
    float sa = 0.f, sd = 0.f;
    #pragma unroll
    for (int c = 0; c < 12; c++) { sa += xp_[c]*as_s[h*12+c]; sd += xp_[c]*ad_s[h*12+c]; }
    union { _Float16 hh[16]; float ff[8]; float4 f4[2]; } s;
    #pragma unroll
    for (int c = 0; c < 12; c++) s.hh[c] = (_Float16)xp_[c];
    s.ff[6] = sa;
    s.ff[7] = sd;
    float4* o = (float4*)(xpp + (size_t)gid * 16);
    o[0] = s.f4[0];
    o[1] = s.f4[1];
}

// ---------------- 2a. 8-bit LDS histogram rank builder (single pass, all 64K nodes) ----------------
// deg ~ Poisson(16) (max ~50) so every count/offset fits a byte; per-(slice,node)
// count <= ~6. 128 slices x 8192 edges; rank8 packs 4 edge-ranks per word.
// Round-18: 512 threads (64KB LDS caps at 128 blocks on 128 CUs; doubling
// waves/block halves the zero/process/writeout phase walls).
__global__ __launch_bounds__(512)
void edge_hist(const int* __restrict__ ei, unsigned* __restrict__ cnt,
               unsigned* __restrict__ rank8)
{
    __shared__ unsigned hist[16384];           // 64 KB: 65536 nodes x 8-bit
    int tid = threadIdx.x;
    int slice = blockIdx.x;                    // 0..127
    for (int i = tid; i < 16384; i += 512) hist[i] = 0;
    __syncthreads();
    const i4v* dst4 = (const i4v*)(ei + N_EDGES_C) + slice*2048;
    for (int i = tid; i < 2048; i += 512) {
        i4v d = __builtin_nontemporal_load(&dst4[i]);
        int dd[4] = {d.x, d.y, d.z, d.w};
        unsigned packed = 0;
        #pragma unroll
        for (int j = 0; j < 4; j++) {
            int dj = dd[j];
            unsigned sh = (unsigned)(dj & 3) << 3;
            unsigned old = atomicAdd(&hist[dj >> 2], 1u << sh);
            packed |= ((old >> sh) & 0xffu) << (j*8);
        }
        __builtin_nontemporal_store(packed, &rank8[slice*2048 + i]);
    }
    __syncthreads();
    unsigned* cg = cnt + (size_t)slice*16384;
    for (int i = tid; i < 16384; i += 512) cg[i] = hist[i];
}

// ---------------- 2b. SWAR slice prefix + block-local exclusive rowptr scan ----------------
// Each thread holds its 4 node degrees in `run`'s byte lanes; 32-deep load
// batching pays strided latency 4x instead of 128x. Writes rowptr WITHOUT
// chunk offset + 128 chunk sums. Bit-identical rowptr vs serial scan.
__global__ __launch_bounds__(128)
void slice_prefix(unsigned* __restrict__ cnt, int* __restrict__ rowptr,
                  int* __restrict__ chunksum)
{
    __shared__ int ss[128];
    int tid = threadIdx.x;
    int w = blockIdx.x*128 + tid;              // 0..16383, 4 nodes per word
    unsigned run = 0;
    unsigned* base = cnt + w;
    #pragma unroll 1
    for (int s = 0; s < 128; s += 32) {        // 32-deep load batching
        unsigned v[32];
        #pragma unroll
        for (int k = 0; k < 32; k++) v[k] = base[(size_t)(s+k)*16384];
        #pragma unroll
        for (int k = 0; k < 32; k++) {
            base[(size_t)(s+k)*16384] = run;
            run += v[k];                        // byte-lane add, carry-free
        }
    }
    int d0 = (int)(run & 255u), d1 = (int)((run >> 8) & 255u);
    int d2 = (int)((run >> 16) & 255u), d3 = (int)(run >> 24);
    int tsum = d0 + d1 + d2 + d3;
    ss[tid] = tsum;
    __syncthreads();
    for (int off = 1; off < 128; off <<= 1) {
        int t = (tid >= off) ? ss[tid - off] : 0;
        __syncthreads();
        ss[tid] += t;
        __syncthreads();
    }
    int ex = ss[tid] - tsum;                   // block-exclusive prefix
    int4 r;
    r.x = ex;
    r.y = ex + d0;
    r.z = ex + d0 + d1;
    r.w = ex + d0 + d1 + d2;
    ((int4*)rowptr)[w] = r;
    if (tid == 127) chunksum[blockIdx.x] = ss[127];
}

// ---------------- 2c-1. scan 128 chunk sums (tiny) ----------------
__global__ void scan_mid(const int* __restrict__ chunksum, int* __restrict__ chunkoff,
                         int* __restrict__ rowptr)
{
    __shared__ int ss[128];
    int tid = threadIdx.x;
    int v = chunksum[tid];
    ss[tid] = v;
    __syncthreads();
    for (int off = 1; off < 128; off <<= 1) {
        int t = (tid >= off) ? ss[tid - off] : 0;
        __syncthreads();
        ss[tid] += t;
        __syncthreads();
    }
    chunkoff[tid] = ss[tid] - v;
    if (tid == 127) rowptr[65536] = ss[127];
}

// ---------------- 2c-2. add chunk offsets (128 blocks) + zero X1 for gemm_x1 atomics ----------------
__global__ __launch_bounds__(128)
void scan_out(const int* __restrict__ chunkoff, int* __restrict__ rowptr,
              float* __restrict__ X1)
{
    int w = blockIdx.x*128 + threadIdx.x;
    int off = chunkoff[blockIdx.x];
    int4 r = ((int4*)rowptr)[w];
    r.x += off; r.y += off; r.z += off; r.w += off;
    ((int4*)rowptr)[w] = r;
    // side job: zero X1 (49152 floats = 16384 thr x 3, coalesced stride)
    X1[w] = 0.f; X1[w + 16384] = 0.f; X1[w + 32768] = 0.f;
}

// ---------------- 2d. read-once LDS-staged CSR scatter ----------------
__global__ __launch_bounds__(256)
void edge_scatter(const int* __restrict__ ei, const unsigned* __restrict__ rank8,
                  const unsigned* __restrict__ cnt, const int* __restrict__ rowptr,
                  int* __restrict__ csr)
{
    __shared__ unsigned pos_s[2048];           // pos | (dst-group << 24)
    __shared__ int src_s[2048];
    int slice = blockIdx.x >> 2;               // 0..127
    int quar  = blockIdx.x & 3;                // 0..3
    int base = slice*2048 + quar*512;          // i4v units
    const i4v* dst4 = (const i4v*)(ei + N_EDGES_C);
    const i4v* src4 = (const i4v*)ei;
    const unsigned* cslice = cnt + (size_t)slice*16384;
    for (int i = threadIdx.x; i < 512; i += 256) {
        int idx = base + i;
        i4v d = __builtin_nontemporal_load(&dst4[idx]);
        i4v s = __builtin_nontemporal_load(&src4[idx]);
        unsigned r = __builtin_nontemporal_load(&rank8[idx]);
        int dd[4] = {d.x, d.y, d.z, d.w};
        int ss[4] = {s.x, s.y, s.z, s.w};
        #pragma unroll
        for (int j = 0; j < 4; j++) {
            int dj = dd[j];
            unsigned word = cslice[dj >> 2];
            int so = (int)((word >> ((unsigned)(dj & 3) << 3)) & 0xffu);
            int rk = (int)((r >> (j*8)) & 0xffu);
            unsigned pos = (unsigned)(rowptr[dj] + so + rk);
            pos_s[i*4 + j] = pos | ((unsigned)(dj >> 13) << 24);
            src_s[i*4 + j] = ss[j];
        }
    }
    __syncthreads();
    #pragma unroll 1
    for (unsigned g = 0; g < 8; g++) {
        for (int e = threadIdx.x; e < 2048; e += 256) {
            unsigned pw = pos_s[e];
            if ((pw >> 24) == g) csr[pw & 0xFFFFFFu] = src_s[e];
        }
    }
}

// ---------------- 3. per-(node,head) softmax aggregation + BN + log_softmax ----------------
// Round-2 proven form: node-major gathers (8 lanes share a 256B row -> 2
// coalesced 128B requests/edge), x4 neighbor unroll, fused shfl-mean +
// BN + log_softmax. 44 us ~= 117 MB compulsory / 2.7 TB/s fabric rate.
__global__ void gat_aggregate(const _Float16* __restrict__ xpp,
                              const int* __restrict__ rowptr, const int* __restrict__ csr_src,
                              const float* __restrict__ gat_bias, const float* __restrict__ bn_gamma,
                              const float* __restrict__ bn_beta, const float* __restrict__ bn_mean,
                              const float* __restrict__ bn_var, float* __restrict__ seq)
{
    int gid = blockIdx.x * 256 + threadIdx.x;
    int n = gid >> 3;
    int h = gid & 7;

    float acc[12];
    float adst_n, d;
    {
        const float4* p = (const float4*)(xpp + (size_t)n*128 + h*16);
        float4 f0 = p[0], f1 = p[1];
        adst_n = f1.w;
        float w = __expf(lrelu(f1.z + adst_n));   // self-loop term
        d = w;
        h2v c0 = __builtin_bit_cast(h2v, f0.x), c1 = __builtin_bit_cast(h2v, f0.y);
        h2v c2 = __builtin_bit_cast(h2v, f0.z), c3 = __builtin_bit_cast(h2v, f0.w);
        h2v c4 = __builtin_bit_cast(h2v, f1.x), c5 = __builtin_bit_cast(h2v, f1.y);
        acc[0]=w*(float)c0.x; acc[1]=w*(float)c0.y; acc[2]=w*(float)c1.x; acc[3]=w*(float)c1.y;
        acc[4]=w*(float)c2.x; acc[5]=w*(float)c2.y; acc[6]=w*(float)c3.x; acc[7]=w*(float)c3.y;
        acc[8]=w*(float)c4.x; acc[9]=w*(float)c4.y; acc[10]=w*(float)c5.x; acc[11]=w*(float)c5.y;
    }

    auto accum = [&](float4 f0, float4 f1) {
        float w = __expf(lrelu(f1.z + adst_n));
        d += w;
        h2v c0 = __builtin_bit_cast(h2v, f0.x), c1 = __builtin_bit_cast(h2v, f0.y);
        h2v c2 = __builtin_bit_cast(h2v, f0.z), c3 = __builtin_bit_cast(h2v, f0.w);
        h2v c4 = __builtin_bit_cast(h2v, f1.x), c5 = __builtin_bit_cast(h2v, f1.y);
        acc[0]+=w*(float)c0.x; acc[1]+=w*(float)c0.y; acc[2]+=w*(float)c1.x; acc[3]+=w*(float)c1.y;
        acc[4]+=w*(float)c2.x; acc[5]+=w*(float)c2.y; acc[6]+=w*(float)c3.x; acc[7]+=w*(float)c3.y;
        acc[8]+=w*(float)c4.x; acc[9]+=w*(float)c4.y; acc[10]+=w*(float)c5.x; acc[11]+=w*(float)c5.y;
    };

    int beg = rowptr[n], end = rowptr[n+1];
    const _Float16* xh = xpp + (size_t)h * 16;
    int i = beg;
    for (; i + 4 <= end; i += 4) {
        int s0 = csr_src[i+0];
        int s1 = csr_src[i+1];
        int s2 = csr_src[i+2];
        int s3 = csr_src[i+3];
        const float4* p0 = (const float4*)(xh + (size_t)s0*128);
        const float4* p1 = (const float4*)(xh + (size_t)s1*128);
        const float4* p2 = (const float4*)(xh + (size_t)s2*128);
        const float4* p3 = (const float4*)(xh + (size_t)s3*128);
        float4 a0 = p0[0], b0 = p0[1];
        float4 a1 = p1[0], b1 = p1[1];
        float4 a2 = p2[0], b2 = p2[1];
        float4 a3 = p3[0], b3 = p3[1];
        accum(a0, b0);
        accum(a1, b1);
        accum(a2, b2);
        accum(a3, b3);
    }
    for (; i < end; i++) {
        int src = csr_src[i];
        const float4* p = (const float4*)(xh + (size_t)src*128);
        float4 f0 = p[0], f1 = p[1];
        accum(f0, f1);
    }

    float inv = 1.0f / (d + 1e-16f);
    float res[12];
    #pragma unroll
    for (int c = 0; c < 12; c++) {
        float v = acc[c] * inv;
        v += __shfl_xor(v, 1);
        v += __shfl_xor(v, 2);
        v += __shfl_xor(v, 4);
        res[c] = v * 0.125f;     // mean over 8 heads
    }
    if (h == 0) {
        float vals[12];
        float mx = -1e30f;
        #pragma unroll
        for (int c = 0; c < 12; c++) {
            float v = res[c] + gat_bias[c];
            v = (v - bn_mean[c]) * rsqrtf(bn_var[c] + 1e-5f) * bn_gamma[c] + bn_beta[c];
            vals[c] = v;
            mx = fmaxf(mx, v);
        }
        float sum = 0.f;
        #pragma unroll
        for (int c = 0; c < 12; c++) sum += __expf(vals[c] - mx);
        float lse = __logf(sum) + mx;
        #pragma unroll
        for (int c = 0; c < 12; c++) seq[(size_t)c * N_TOTAL_C + n] = vals[c] - lse;
    }
}

// ---------------- 4. X1 = seq(384x2048) @ w_ih1(128x2048)^T, split-K x16 ----------------
// Round-18 re-tile: 32x64 tile, K-chunk 128, grid (12,2,16)=384 blocks
// (>=256 CUs, 3 blocks/CU by LDS), 8 outputs/thread (2 rows x 4 cols):
// 1024 MAC/thread, 8 FMA per 6 LDS reads. Pad-129 rows: As hits 4 distinct
// banks (broadcast x16 lanes), Bs 2-way (free, m136). Same split-K=16 and
// ascending-k order per output -> absmax unchanged.
__global__ __launch_bounds__(256)
void gemm_x1(const float* __restrict__ A, const float* __restrict__ B,
             float* __restrict__ C)
{
    __shared__ float As[32][129];
    __shared__ float Bs[64][129];
    const int K = 2048, N = 128;
    int tid = threadIdx.x;
    int bm = blockIdx.x * 32, bn = blockIdx.y * 64;
    int k0 = blockIdx.z * 128;
    #pragma unroll
    for (int t = 0; t < 16; t++) {             // A tile 32x128
        int idx = tid + t*256;
        As[idx >> 7][idx & 127] = A[(size_t)(bm + (idx >> 7)) * K + k0 + (idx & 127)];
    }
    #pragma unroll
    for (int t = 0; t < 32; t++) {             // B tile 64x128
        int idx = tid + t*256;
        Bs[idx >> 7][idx & 127] = B[(size_t)(bn + (idx >> 7)) * K + k0 + (idx & 127)];
    }
    __syncthreads();
    int cg = tid & 15;                         // cols cg*4 .. cg*4+3
    int rg = tid >> 4;                         // rows rg*2, rg*2+1
    float acc[2][4] = {};
    #pragma unroll 4
    for (int k = 0; k < 128; k++) {
        float a0 = As[rg*2][k],   a1 = As[rg*2+1][k];
        float b0 = Bs[cg*4+0][k], b1 = Bs[cg*4+1][k];
        float b2 = Bs[cg*4+2][k], b3 = Bs[cg*4+3][k];
        acc[0][0] += a0*b0; acc[0][1] += a0*b1; acc[0][2] += a0*b2; acc[0][3] += a0*b3;
        acc[1][0] += a1*b0; acc[1][1] += a1*b1; acc[1][2] += a1*b2; acc[1][3] += a1*b3;
    }
    #pragma unroll
    for (int i = 0; i < 2; i++)
        #pragma unroll
        for (int j = 0; j < 4; j++)
            atomicAdd(&C[(size_t)(bm + rg*2 + i) * N + bn + cg*4 + j], acc[i][j]);
}

// ---------------- 5. fused LSTM1(2048->32) + LSTM2(32->128) ----------------
__global__ __launch_bounds__(512)
void lstm_fused(const float* __restrict__ X1, const float* __restrict__ w_hh1,
                const float* __restrict__ b_ih1, const float* __restrict__ b_hh1,
                const float* __restrict__ w_ih2, const float* __restrict__ w_hh2,
                const float* __restrict__ b_ih2, const float* __restrict__ b_hh2,
                float* __restrict__ H2)
{
    __shared__ float whh1[128*33];             // padded stride 33
    __shared__ float b1s[128];
    __shared__ float h1[32], c1[32];
    __shared__ __align__(16) _Float16 h1s[32];
    __shared__ __align__(16) _Float16 h2s[128];
    __shared__ float c2[128];
    __shared__ float g1s[128], g2s[512];
    int tid = threadIdx.x;
    int b = blockIdx.x;

    h2v whh[64];
    {
        const float2* wh = (const float2*)(w_hh2 + (size_t)tid * 128);
        #pragma unroll
        for (int k = 0; k < 64; k++) {
            float2 v = wh[k];
            h2v t; t.x = (_Float16)v.x; t.y = (_Float16)v.y;
            whh[k] = t;
        }
    }
    h2v wih[16];
    {
        const float2* wi = (const float2*)(w_ih2 + (size_t)tid * 32);
        #pragma unroll
        for (int k = 0; k < 16; k++) {
            float2 v = wi[k];
            h2v t; t.x = (_Float16)v.x; t.y = (_Float16)v.y;
            wih[k] = t;
        }
    }
    float b2 = b_ih2[tid] + b_hh2[tid];

    for (int i = tid; i < 128*32; i += 512) whh1[(i >> 5)*33 + (i & 31)] = w_hh1[i];
    if (tid < 128) b1s[tid] = b_ih1[tid] + b_hh1[tid];
    if (tid < 32)  { h1[tid] = 0.f; c1[tid] = 0.f; h1s[tid] = (_Float16)0.f; }
    if (tid < 128) { c2[tid] = 0.f; h2s[tid] = (_Float16)0.f; }

    float xv = 0.f;
    if (tid < 128) xv = X1[((size_t)0*32 + b)*128 + tid];   // t=0 row
    __syncthreads();

    for (int t = 0; t < 12; t++) {
        float xv_next = 0.f;
        if (t < 11 && tid < 128) xv_next = X1[((size_t)(t+1)*32 + b)*128 + tid];

        float p0 = b2, p1 = 0.f, p2 = 0.f, p3 = 0.f;
        #pragma unroll
        for (int j = 0; j < 16; j++) {
            float4 f = ((const float4*)h2s)[j];
            p0 = fdot2(__builtin_bit_cast(h2v, f.x), whh[j*4+0], p0);
            p1 = fdot2(__builtin_bit_cast(h2v, f.y), whh[j*4+1], p1);
            p2 = fdot2(__builtin_bit_cast(h2v, f.z), whh[j*4+2], p2);
            p3 = fdot2(__builtin_bit_cast(h2v, f.w), whh[j*4+3], p3);
        }
        float acc2 = (p0 + p1) + (p2 + p3);

        if (tid < 128) {
            const float* wr = &whh1[tid * 33];
            float acc = xv + b1s[tid];
            #pragma unroll
            for (int k = 0; k < 32; k++) acc += h1[k] * wr[k];
            g1s[tid] = acc;
        }
        __syncthreads();
        if (tid < 32) {
            float ig = sigf(g1s[tid]), fg = sigf(g1s[32+tid]);
            float gg = tanh_fast(g1s[64+tid]), og = sigf(g1s[96+tid]);
            float cn = fg * c1[tid] + ig * gg;
            c1[tid] = cn;
            float hn = og * tanh_fast(cn);
            h1[tid] = hn;
            h1s[tid] = (_Float16)hn;
        }
        __syncthreads();
        {
            float q0 = 0.f, q1 = 0.f, q2 = 0.f, q3 = 0.f;
            #pragma unroll
            for (int j = 0; j < 4; j++) {
                float4 f = ((const float4*)h1s)[j];
                q0 = fdot2(__builtin_bit_cast(h2v, f.x), wih[j*4+0], q0);
                q1 = fdot2(__builtin_bit_cast(h2v, f.y), wih[j*4+1], q1);
                q2 = fdot2(__builtin_bit_cast(h2v, f.z), wih[j*4+2], q2);
                q3 = fdot2(__builtin_bit_cast(h2v, f.w), wih[j*4+3], q3);
            }
            g2s[tid] = acc2 + (q0 + q1) + (q2 + q3);
        }
        __syncthreads();
        if (tid < 128) {
            float ig = sigf(g2s[tid]), fg = sigf(g2s[128+tid]);
            float gg = tanh_fast(g2s[256+tid]), og = sigf(g2s[384+tid]);
            float cn = fg * c2[tid] + ig * gg;
            c2[tid] = cn;
            float hn = og * tanh_fast(cn);
            h2s[tid] = (_Float16)hn;
            if (t >= 3) H2[((size_t)t*32 + b)*128 + tid] = hn;
        }
        __syncthreads();
        xv = xv_next;
    }
}

// ---------------- 6. out = H2[3:] (288x128) @ lin_w(2048x128)^T + lin_b ----------------
__global__ void gemm_out(const float* __restrict__ A, const float* __restrict__ B,
                         const float* __restrict__ bias, float* __restrict__ out)
{
    __shared__ float As[32][33], Bs[32][33];
    const int K = 128;
    int tid = threadIdx.x;
    int tx = tid & 31, ty = tid >> 5;
    int bm = blockIdx.x * 32, bn = blockIdx.y * 32;
    float acc[4] = {0.f,0.f,0.f,0.f};
    for (int k0 = 0; k0 < K; k0 += 32) {
        #pragma unroll
        for (int i = 0; i < 4; i++) {
            int r = ty + i*8;
            As[r][tx] = A[(size_t)(bm + r) * K + k0 + tx];
            Bs[r][tx] = B[(size_t)(bn + r) * K + k0 + tx];
        }
        __syncthreads();
        #pragma unroll
        for (int kk = 0; kk < 32; kk++) {
            float bv = Bs[tx][kk];
            #pragma unroll
            for (int i = 0; i < 4; i++) acc[i] += As[ty + i*8][kk] * bv;
        }
        __syncthreads();
    }
    int j = blockIdx.x;            // time slot within last 9
    int nn = bn + tx;
    float bv = bias[nn];
    #pragma unroll
    for (int i = 0; i < 4; i++) {
        int bb = ty + i*8;
        out[((size_t)bb * 2048 + nn) * 9 + j] = acc[i] + bv;
    }
}

extern "C" void kernel_launch(void* const* d_in, const int* in_sizes, int n_in,
                              void* d_out, int out_size, void* d_ws, size_t ws_size,
                              hipStream_t stream)
{
    const float* x        = (const float*)d_in[0];
    const int*   ei       = (const int*)  d_in[1];
    const float* W_gat    = (const float*)d_in[2];
    const float* a_src    = (const float*)d_in[3];
    const float* a_dst    = (const float*)d_in[4];
    const float* gat_bias = (const float*)d_in[5];
    const float* bn_gamma = (const float*)d_in[6];
    const float* bn_beta  = (const float*)d_in[7];
    const float* bn_mean  = (const float*)d_in[8];
    const float* bn_var   = (const float*)d_in[9];
    const float* w_ih1    = (const float*)d_in[10];
    const float* w_hh1    = (const float*)d_in[11];
    const float* b_ih1    = (const float*)d_in[12];
    const float* b_hh1    = (const float*)d_in[13];
    const float* w_ih2    = (const float*)d_in[14];
    const float* w_hh2    = (const float*)d_in[15];
    const float* b_ih2    = (const float*)d_in[16];
    const float* b_hh2    = (const float*)d_in[17];
    const float* lin_w    = (const float*)d_in[18];
    const float* lin_b    = (const float*)d_in[19];
    float* out = (float*)d_out;

    float* ws = (float*)d_ws;                     // all offsets in float slots (x4 bytes)
    _Float16* xpp = (_Float16*)ws;                // 65536*128 halfs = 4194304 slots (16 MB, node-major)
    float* seq  = ws + 4194304;                   // 786432
    float* X1   = seq + 786432;                   // 49152
    float* H2   = X1  + 49152;                    // 49152
    int* rowptr = (int*)(H2 + 49152);             // 65537 (reserve 65544, 16B-aligned)
    int* deg    = rowptr + 65544;                 // 65536 (reused: chunksum[128], chunkoff[128])
    unsigned* cnt = (unsigned*)(deg + 65536);     // 128*16384 = 2097152 words (8 MB)
    unsigned* rank8 = cnt + 2097152;              // 262144 words (1 MB)
    int* csr    = (int*)(rank8 + 262144);         // 1048576
    // total ~34 MB of d_ws

    int* chunksum = deg;
    int* chunkoff = deg + 128;

    prep_kernel <<<2048, 256, 0, stream>>>(x, W_gat, a_src, a_dst, xpp);
    edge_hist   <<<128, 512, 0, stream>>>(ei, cnt, rank8);
    slice_prefix<<<128, 128, 0, stream>>>(cnt, rowptr, chunksum);
    scan_mid    <<<1, 128, 0, stream>>>(chunksum, chunkoff, rowptr);
    scan_out    <<<128, 128, 0, stream>>>(chunkoff, rowptr, X1);
    edge_scatter<<<512, 256, 0, stream>>>(ei, rank8, cnt, rowptr, csr);
    gat_aggregate<<<2048, 256, 0, stream>>>(xpp, rowptr, csr,
                                            gat_bias, bn_gamma, bn_beta, bn_mean, bn_var, seq);
    gemm_x1<<<dim3(12, 2, 16), 256, 0, stream>>>(seq, w_ih1, X1);
    lstm_fused<<<32, 512, 0, stream>>>(X1, w_hh1, b_ih1, b_hh1, w_ih2, w_hh2, b_ih2, b_hh2, H2);
    gemm_out<<<dim3(9, 64), 256, 0, stream>>>(H2 + 96*128, lin_w, lin_b, out);
}